// Round 2
// baseline (412.075 us; speedup 1.0000x reference)
//
#include <hip/hip_runtime.h>

#define LM 64      // L_MODES
#define MM 127     // 2L-1
#define GG 128     // GRID (theta and lon, in and out)
#define CC 64      // CIN
#define OO 64      // COUT

#define TWO_PI 6.28318530717958647692f

// K0: aux = [psi(128) | tvec(64) | cwsum(64) | bsum(1)]
// psi = t_emb @ dense_w ; tvec[o] = sum_j time_w[o,j]*psi[j] ;
// cwsum[c] = sum_o conv_w[c,o] ; bsum = sum_o conv_b[o]
__global__ void k_pre(const float* __restrict__ t_emb, const float* __restrict__ dense_w,
                      const float* __restrict__ time_w, const float* __restrict__ conv_w,
                      const float* __restrict__ conv_b, float* __restrict__ aux) {
    __shared__ float psis[128];
    int j = threadIdx.x; // 0..127
    float acc = 0.f;
    for (int t = 0; t < 256; ++t) acc += t_emb[t] * dense_w[t * 128 + j];
    psis[j] = acc;
    aux[j] = acc;
    __syncthreads();
    if (j < 64) {
        float tv = 0.f;
        for (int q = 0; q < 64; ++q) tv += time_w[j * 64 + q] * psis[q];
        aux[128 + j] = tv;
        float cs = 0.f;
        for (int o = 0; o < 64; ++o) cs += conv_w[j * 64 + o];
        aux[192 + j] = cs;
        if (j == 0) {
            float bs = 0.f;
            for (int o = 0; o < 64; ++o) bs += conv_b[o];
            aux[256] = bs;
        }
    }
}

// K1: DFT over longitude, bins k=0..63, times (2pi/G)*quad_w[t].
// F[(t*64+k)*CC + c] = sum_n x[t,n,c] * e^{-2pi i k n / G} * scale_t
__global__ void k_dft(const float* __restrict__ x, const float* __restrict__ quad_w,
                      float2* __restrict__ F) {
    int t = blockIdx.x, k = blockIdx.y, c = threadIdx.x;
    __shared__ float2 tab[GG];
    for (int j = c; j < GG; j += 64) {
        float ang = (TWO_PI / GG) * j;
        tab[j] = make_float2(__cosf(ang), __sinf(ang));
    }
    __syncthreads();
    float sr = 0.f, si = 0.f;
    int kn = 0;
    for (int n = 0; n < GG; ++n) {
        float v = x[(t * GG + n) * CC + c];
        float2 w = tab[kn];
        sr += v * w.x;
        si -= v * w.y;
        kn = (kn + k) & (GG - 1);
    }
    float sc = (TWO_PI / GG) * quad_w[t];
    F[(t * 64 + k) * CC + c] = make_float2(sr * sc, si * sc);
}

// K2: forward Legendre, m >= 0 only, l >= m only.
// flm[(l*64+m)*CC+c] = sum_t F[t,m,c] * P_in[l, 63+m, t]
__global__ void k_leg_fwd(const float2* __restrict__ F, const float* __restrict__ P_in,
                          float2* __restrict__ flm) {
    int l = blockIdx.x, m = blockIdx.y, c = threadIdx.x;
    if (l < m) return;
    const float* P = P_in + (l * MM + 63 + m) * GG;
    float sr = 0.f, si = 0.f;
    for (int t = 0; t < GG; ++t) {
        float p = P[t];
        float2 f = F[(t * 64 + m) * CC + c];
        sr += f.x * p;
        si += f.y * p;
    }
    flm[(l * 64 + m) * CC + c] = make_float2(sr, si);
}

// K3: complex channel mix per (l, mi). Negative m from conj symmetry:
// flm[l,-m] = (-1)^m conj(flm[l,m]).  flm2[l,mi,o] = sum_i flm_pm[i] * (wr+i wi)[l,mi,i,o]
__global__ void k_wmul(const float2* __restrict__ flm, const float* __restrict__ wr,
                       const float* __restrict__ wi, float2* __restrict__ flm2) {
    int l = blockIdx.x, mi = blockIdx.y, o = threadIdx.x;
    int m = mi - 63;
    int am = m < 0 ? -m : m;
    if (l < am) return;
    __shared__ float2 fs[CC];
    {
        float2 f = flm[(l * 64 + am) * CC + o];
        if (m < 0) {
            float sgn = (am & 1) ? -1.f : 1.f;
            f.x *= sgn;
            f.y *= -sgn;
        }
        fs[o] = f;
    }
    __syncthreads();
    const float* wrp = wr + (size_t)((l * MM + mi) * CC) * OO + o;
    const float* wip = wi + (size_t)((l * MM + mi) * CC) * OO + o;
    float ar = 0.f, ai = 0.f;
    for (int i = 0; i < CC; ++i) {
        float2 f = fs[i];
        float a = wrp[(size_t)i * OO];
        float b = wip[(size_t)i * OO];
        ar += f.x * a - f.y * b;
        ai += f.x * b + f.y * a;
    }
    flm2[(l * MM + mi) * OO + o] = make_float2(ar, ai);
}

// K4: inverse Legendre. g[t,mi,o] = sum_{l=|m|}^{63} flm2[l,mi,o] * P_out[l,mi,t]
__global__ void k_leg_inv(const float2* __restrict__ flm2, const float* __restrict__ P_out,
                          float2* __restrict__ g) {
    int t = blockIdx.x, mi = blockIdx.y, o = threadIdx.x;
    int m = mi - 63;
    int am = m < 0 ? -m : m;
    float sr = 0.f, si = 0.f;
    for (int l = am; l < LM; ++l) {
        float p = P_out[(l * MM + mi) * GG + t];
        float2 f = flm2[(l * MM + mi) * OO + o];
        sr += f.x * p;
        si += f.y * p;
    }
    g[(t * MM + mi) * OO + o] = make_float2(sr, si);
}

// K5: Fourier synthesis (real part) + decoupled conv/time branch + LayerNorm + ReLU.
// val[t,k,o] = x_spec + tvec[o] * (bsum + sum_c x[t,k,c]*cwsum[c]) + b_t[o]
__global__ void k_final(const float2* __restrict__ g, const float* __restrict__ x,
                        const float* __restrict__ aux,
                        const float* __restrict__ ln_scale, const float* __restrict__ ln_bias,
                        float* __restrict__ out) {
    int t = blockIdx.x, k = blockIdx.y, o = threadIdx.x;
    __shared__ float2 tab[GG];
    __shared__ float xs[CC];
    __shared__ float cws[CC];
    for (int j = o; j < GG; j += 64) {
        float ang = (TWO_PI / GG) * j;
        tab[j] = make_float2(__cosf(ang), __sinf(ang));
    }
    xs[o] = x[(t * GG + k) * CC + o];
    cws[o] = aux[192 + o];
    __syncthreads();

    // x_spec[t,k,o] = sum_mi gr*cos(m*phi_k) - gi*sin(m*phi_k), m = mi-63
    float xsp = 0.f;
    int idx = (-63 * k) % GG;
    if (idx < 0) idx += GG;
    const float2* gp = g + (size_t)t * MM * OO + o;
    for (int mi = 0; mi < MM; ++mi) {
        float2 w = tab[idx];
        float2 gv = gp[(size_t)mi * OO];
        xsp += gv.x * w.x - gv.y * w.y;
        idx = (idx + k) & (GG - 1);
    }

    // channel-sum of conv output: S = bsum + sum_c xs[c]*cwsum[c]
    float S = aux[256];
    for (int c = 0; c < CC; ++c) S += xs[c] * cws[c];

    float val = xsp + aux[128 + o] * S + aux[64 + o];

    // LayerNorm over 64 channels == 64 lanes (one wave)
    float mu = val;
    for (int off = 1; off < 64; off <<= 1) mu += __shfl_xor(mu, off);
    mu *= (1.f / 64.f);
    float d = val - mu;
    float var = d * d;
    for (int off = 1; off < 64; off <<= 1) var += __shfl_xor(var, off);
    var *= (1.f / 64.f);
    float r = (val - mu) * rsqrtf(var + 1e-6f) * ln_scale[o] + ln_bias[o];
    out[((size_t)t * GG + k) * OO + o] = fmaxf(r, 0.f);
}

extern "C" void kernel_launch(void* const* d_in, const int* in_sizes, int n_in,
                              void* d_out, int out_size, void* d_ws, size_t ws_size,
                              hipStream_t stream) {
    const float* x        = (const float*)d_in[0];
    const float* t_emb    = (const float*)d_in[1];
    const float* wr       = (const float*)d_in[2];
    const float* wi       = (const float*)d_in[3];
    const float* conv_w   = (const float*)d_in[4];
    const float* conv_b   = (const float*)d_in[5];
    const float* time_w   = (const float*)d_in[6];
    const float* dense_w  = (const float*)d_in[7];
    const float* ln_scale = (const float*)d_in[8];
    const float* ln_bias  = (const float*)d_in[9];
    const float* P_in     = (const float*)d_in[10];
    const float* P_out    = (const float*)d_in[11];
    const float* quad_w   = (const float*)d_in[12];

    float* ws = (float*)d_ws;
    float*  aux  = ws;                                    // 512 floats (psi|tvec|cwsum|bsum)
    float2* F    = (float2*)(ws + 512);                   // 128*64*64 float2
    float2* flm  = (float2*)(ws + 512 + 1048576);         // 64*64*64 float2
    float2* flm2 = (float2*)(ws + 512 + 1048576 + 524288);           // 64*127*64 float2
    float2* g    = (float2*)(ws + 512 + 1048576 + 524288 + 1040384); // 128*127*64 float2

    float* out = (float*)d_out;

    k_pre<<<1, 128, 0, stream>>>(t_emb, dense_w, time_w, conv_w, conv_b, aux);
    k_dft<<<dim3(GG, 64), 64, 0, stream>>>(x, quad_w, F);
    k_leg_fwd<<<dim3(LM, 64), 64, 0, stream>>>(F, P_in, flm);
    k_wmul<<<dim3(LM, MM), 64, 0, stream>>>(flm, wr, wi, flm2);
    k_leg_inv<<<dim3(GG, MM), 64, 0, stream>>>(flm2, P_out, g);
    k_final<<<dim3(GG, GG), 64, 0, stream>>>(g, x, aux, ln_scale, ln_bias, out);
}

// Round 3
// 364.815 us; speedup vs baseline: 1.1295x; 1.1295x over previous
//
#include <hip/hip_runtime.h>
#include <math.h>

#define LM 64      // L_MODES
#define MM 127     // 2L-1
#define GG 128     // GRID
#define CC 64      // CIN
#define OO 64      // COUT

#define TWO_PI 6.28318530717958647692f

// ---------------------------------------------------------------------------
// K0: aux = [psi(128) | tvec(64) | cwsum(64) | bsum(1)]
__global__ void k_pre(const float* __restrict__ t_emb, const float* __restrict__ dense_w,
                      const float* __restrict__ time_w, const float* __restrict__ conv_w,
                      const float* __restrict__ conv_b, float* __restrict__ aux) {
    __shared__ float psis[128];
    int j = threadIdx.x; // 0..127
    float acc = 0.f;
    for (int t = 0; t < 256; ++t) acc += t_emb[t] * dense_w[t * 128 + j];
    psis[j] = acc;
    aux[j] = acc;
    __syncthreads();
    if (j < 64) {
        float tv = 0.f;
        for (int q = 0; q < 64; ++q) tv += time_w[j * 64 + q] * psis[q];
        aux[128 + j] = tv;
        float cs = 0.f;
        for (int o = 0; o < 64; ++o) cs += conv_w[j * 64 + o];
        aux[192 + j] = cs;
        if (j == 0) {
            float bs = 0.f;
            for (int o = 0; o < 64; ++o) bs += conv_b[o];
            aux[256] = bs;
        }
    }
}

// ---------------------------------------------------------------------------
// K1: DFT over longitude. Block per t (128 blocks), 512 threads.
// F[(t*64+k)*CC+c] = sum_n x[t,n,c] e^{-i 2pi k n/128} * (2pi/G)*quad_w[t]
__global__ __launch_bounds__(512) void k_dft(const float* __restrict__ x,
                                             const float* __restrict__ quad_w,
                                             float2* __restrict__ F) {
    __shared__ __align__(16) float smem[64 * 65 * 2]; // union: xs[8192] floats | Fbuf[64][65] float2
    __shared__ float2 tab[GG];
    int t = blockIdx.x;
    int tx = threadIdx.x;
    int k = tx & 63, cg = tx >> 6;  // cg 0..7, c0 = cg*8
    int c0 = cg * 8;

    float* xs = smem; // [n][c] 128x64
    // stage x[t] (float4 coalesced)
    {
        const float4* xp = (const float4*)(x + (size_t)t * GG * CC);
        float4* xd = (float4*)xs;
        for (int idx = tx; idx < GG * CC / 4; idx += 512) xd[idx] = xp[idx];
    }
    if (tx < GG) {
        float ang = (TWO_PI / GG) * tx;
        tab[tx] = make_float2(cosf(ang), sinf(ang));
    }
    __syncthreads();

    float sr[8], si[8];
#pragma unroll
    for (int j = 0; j < 8; ++j) { sr[j] = 0.f; si[j] = 0.f; }

    int kn = 0;
    for (int n = 0; n < GG; ++n) {
        float2 w = tab[kn];
        const float4 v0 = *(const float4*)&xs[n * 64 + c0];
        const float4 v1 = *(const float4*)&xs[n * 64 + c0 + 4];
        float vv[8] = {v0.x, v0.y, v0.z, v0.w, v1.x, v1.y, v1.z, v1.w};
#pragma unroll
        for (int j = 0; j < 8; ++j) {
            sr[j] += vv[j] * w.x;
            si[j] -= vv[j] * w.y;
        }
        kn = (kn + k) & (GG - 1);
    }
    float sc = (TWO_PI / GG) * quad_w[t];

    __syncthreads(); // done with xs; reuse as Fbuf
    float2* Fbuf = (float2*)smem; // [k][65]
#pragma unroll
    for (int j = 0; j < 8; ++j)
        Fbuf[k * 65 + c0 + j] = make_float2(sr[j] * sc, si[j] * sc);
    __syncthreads();
    // coalesced global write
    float2* Fo = F + (size_t)t * 64 * CC;
    for (int idx = tx; idx < 64 * CC; idx += 512) {
        int kk = idx >> 6, cc = idx & 63;
        Fo[kk * CC + cc] = Fbuf[kk * 65 + cc];
    }
}

// ---------------------------------------------------------------------------
// K1b: S[t,k] = bsum + sum_c x[t,k,c]*cwsum[c]
__global__ __launch_bounds__(128) void k_conv(const float* __restrict__ x,
                                              const float* __restrict__ aux,
                                              float* __restrict__ Sv) {
    __shared__ float xs[GG * 65];
    __shared__ float cws[CC];
    int t = blockIdx.x, tx = threadIdx.x;
    for (int idx = tx; idx < GG * CC; idx += 128) {
        int kk = idx >> 6, cc = idx & 63;
        xs[kk * 65 + cc] = x[((size_t)t * GG + kk) * CC + cc];
    }
    if (tx < 64) cws[tx] = aux[192 + tx];
    __syncthreads();
    float S = aux[256];
    for (int c = 0; c < CC; ++c) S += xs[tx * 65 + c] * cws[c];
    Sv[t * GG + tx] = S;
}

// ---------------------------------------------------------------------------
// K2: forward Legendre. Block per (m, l-half). 256 threads.
// flm[(l*64+m)*CC+c] = sum_t F[t,m,c] * P_in[l, 63+m, t]
__global__ __launch_bounds__(256) void k_leg_fwd(const float2* __restrict__ F,
                                                 const float* __restrict__ P_in,
                                                 float2* __restrict__ flm) {
    int m = blockIdx.x;      // 0..63
    int lh = blockIdx.y;     // 0..1
    int l0 = lh * 32;
    if (l0 + 31 < m) return; // whole block below diagonal (block-uniform)

    __shared__ __align__(16) float2 Fs[64 * 64];   // [tloc][c] 32 KB
    __shared__ __align__(16) float  Ps[128 * 36];  // [t][lr]   18 KB
    int tx = threadIdx.x;
    int c = tx & 63, lg = tx >> 6; // lg 0..3, 8 l each

    for (int idx = tx; idx < 32 * 128; idx += 256) {
        int lr = idx >> 7, t = idx & 127;
        Ps[t * 36 + lr] = P_in[((size_t)(l0 + lr) * MM + 63 + m) * GG + t];
    }

    float sr[8], si[8];
#pragma unroll
    for (int j = 0; j < 8; ++j) { sr[j] = 0.f; si[j] = 0.f; }

    for (int tp = 0; tp < 2; ++tp) {
        __syncthreads();
        for (int idx = tx; idx < 64 * 64; idx += 256) {
            int tl = idx >> 6, cc = idx & 63;
            Fs[idx] = F[((size_t)(tp * 64 + tl) * 64 + m) * CC + cc];
        }
        __syncthreads();
        for (int tl = 0; tl < 64; ++tl) {
            int t = tp * 64 + tl;
            float2 f = Fs[tl * 64 + c];
            const float* pp = &Ps[t * 36 + lg * 8];
            float4 p0 = *(const float4*)pp;
            float4 p1 = *(const float4*)(pp + 4);
            float pv[8] = {p0.x, p0.y, p0.z, p0.w, p1.x, p1.y, p1.z, p1.w};
#pragma unroll
            for (int j = 0; j < 8; ++j) {
                sr[j] += f.x * pv[j];
                si[j] += f.y * pv[j];
            }
        }
    }
#pragma unroll
    for (int j = 0; j < 8; ++j) {
        int l = l0 + lg * 8 + j;
        if (l >= m) flm[((size_t)l * 64 + m) * CC + c] = make_float2(sr[j], si[j]);
    }
}

// ---------------------------------------------------------------------------
// K3: complex channel mix. Block per (l,mi), 256 threads (4 i-groups of 16).
__global__ __launch_bounds__(256) void k_wmul(const float2* __restrict__ flm,
                                              const float* __restrict__ wr,
                                              const float* __restrict__ wi,
                                              float2* __restrict__ flm2) {
    int l = blockIdx.x, mi = blockIdx.y;
    int m = mi - 63;
    int am = m < 0 ? -m : m;
    if (l < am) return;
    __shared__ float2 fs[CC];
    __shared__ float2 part[4][CC];
    int tx = threadIdx.x, o = tx & 63, ig = tx >> 6;
    if (tx < 64) {
        float2 f = flm[((size_t)l * 64 + am) * CC + tx];
        if (m < 0) {
            float sgn = (am & 1) ? -1.f : 1.f;
            f.x *= sgn;
            f.y *= -sgn;
        }
        fs[tx] = f;
    }
    __syncthreads();
    size_t base = ((size_t)(l * MM + mi) * CC) * OO;
    const float* wrp = wr + base + o;
    const float* wip = wi + base + o;
    float ar = 0.f, ai = 0.f;
#pragma unroll
    for (int ii = 0; ii < 16; ++ii) {
        int i = ig * 16 + ii;
        float a = wrp[(size_t)i * OO];
        float b = wip[(size_t)i * OO];
        float2 f = fs[i];
        ar += f.x * a - f.y * b;
        ai += f.x * b + f.y * a;
    }
    part[ig][o] = make_float2(ar, ai);
    __syncthreads();
    if (tx < 64) {
        float2 r0 = part[0][tx], r1 = part[1][tx], r2 = part[2][tx], r3 = part[3][tx];
        flm2[(size_t)(l * MM + mi) * OO + tx] =
            make_float2(r0.x + r1.x + r2.x + r3.x, r0.y + r1.y + r2.y + r3.y);
    }
}

// ---------------------------------------------------------------------------
// K4: inverse Legendre. Block per (mi, th(2) x oh(2)), 256 threads.
// g[t,mi,o] = sum_l flm2[l,mi,o] * P_out[l,mi,t]  (P_out rows l<|m| are exact zeros)
__global__ __launch_bounds__(256) void k_leg_inv(const float2* __restrict__ flm2,
                                                 const float* __restrict__ P_out,
                                                 float2* __restrict__ g) {
    int mi = blockIdx.x;
    int th = blockIdx.y >> 1, oh = blockIdx.y & 1;
    int t0 = th * 64, o0 = oh * 32;

    __shared__ __align__(16) float2 Ws[64 * 32]; // [l][o-local] 32 KB
    __shared__ __align__(16) float  Ps[64 * 64]; // [l][t-local] 16 KB
    int tx = threadIdx.x;
    int ol = tx & 31, tg = tx >> 5; // tg 0..7, 8 t each
    int o = o0 + ol;

    for (int idx = tx; idx < 64 * 32; idx += 256) {
        int ls = idx >> 5, oo = idx & 31;
        Ws[idx] = flm2[(size_t)(ls * MM + mi) * OO + o0 + oo];
    }
    for (int idx = tx; idx < 64 * 64; idx += 256) {
        int ls = idx >> 6, tt = idx & 63;
        Ps[idx] = P_out[((size_t)ls * MM + mi) * GG + t0 + tt];
    }
    __syncthreads();

    float gr[8], gi[8];
#pragma unroll
    for (int j = 0; j < 8; ++j) { gr[j] = 0.f; gi[j] = 0.f; }

    for (int l = 0; l < 64; ++l) {
        float2 wv = Ws[l * 32 + ol];
        const float* pp = &Ps[l * 64 + tg * 8];
        float4 p0 = *(const float4*)pp;
        float4 p1 = *(const float4*)(pp + 4);
        float pv[8] = {p0.x, p0.y, p0.z, p0.w, p1.x, p1.y, p1.z, p1.w};
#pragma unroll
        for (int j = 0; j < 8; ++j) {
            gr[j] += wv.x * pv[j];
            gi[j] += wv.y * pv[j];
        }
    }
#pragma unroll
    for (int j = 0; j < 8; ++j) {
        int t = t0 + tg * 8 + j;
        g[((size_t)t * MM + mi) * OO + o] = make_float2(gr[j], gi[j]);
    }
}

// ---------------------------------------------------------------------------
// K5: Fourier synthesis (Horner on z=e^{i phi_k}) + time-mod branch + LN + ReLU.
// Block per (t, k-half), 512 threads: o = lane, kg = wave id; 8 k per thread.
__global__ __launch_bounds__(512) void k_final(const float2* __restrict__ g,
                                               const float* __restrict__ Sv,
                                               const float* __restrict__ aux,
                                               const float* __restrict__ ln_scale,
                                               const float* __restrict__ ln_bias,
                                               float* __restrict__ out) {
    __shared__ float2 gs[64 * 64]; // 32 KB, staged in two mi-passes
    __shared__ float Ss[64];
    int t = blockIdx.x, kh = blockIdx.y;
    int tx = threadIdx.x;
    int o = tx & 63, kg = tx >> 6; // kg 0..7

    if (tx < 64) Ss[tx] = Sv[t * GG + kh * 64 + tx];

    float zr[8], zi[8], accr[8], acci[8];
#pragma unroll
    for (int j = 0; j < 8; ++j) {
        int k = kh * 64 + kg * 8 + j;
        float phi = (TWO_PI / GG) * k;
        float s, c;
        __sincosf(phi, &s, &c);
        zr[j] = c; zi[j] = s;
        accr[j] = 0.f; acci[j] = 0.f;
    }

    // Horner over mi = 126 .. 0 (descending), staged in two chunks
    for (int pass = 0; pass < 2; ++pass) {
        int mbase = (pass == 0) ? 64 : 0;
        int cnt = (pass == 0) ? 63 : 64;
        __syncthreads();
        for (int idx = tx; idx < cnt * 64; idx += 512) {
            int mm = idx >> 6, oo = idx & 63;
            gs[idx] = g[((size_t)t * MM + mbase + mm) * OO + oo];
        }
        __syncthreads();
        for (int mm = cnt - 1; mm >= 0; --mm) {
            float2 gv = gs[mm * 64 + o];
#pragma unroll
            for (int j = 0; j < 8; ++j) {
                float tr = accr[j] * zr[j] - acci[j] * zi[j] + gv.x;
                float ti = accr[j] * zi[j] + acci[j] * zr[j] + gv.y;
                accr[j] = tr; acci[j] = ti;
            }
        }
    }

    float tvec = aux[128 + o], bt = aux[64 + o];
    float lns = ln_scale[o], lnb = ln_bias[o];
#pragma unroll
    for (int j = 0; j < 8; ++j) {
        int k = kh * 64 + kg * 8 + j;
        float phi = (TWO_PI / GG) * k;
        float s63, c63;
        sincosf(63.f * phi, &s63, &c63);
        float xsp = accr[j] * c63 + acci[j] * s63; // Re(e^{-i63phi} * H)
        float val = xsp + tvec * Ss[k - kh * 64] + bt;

        float mu = val;
#pragma unroll
        for (int off = 1; off < 64; off <<= 1) mu += __shfl_xor(mu, off);
        mu *= (1.f / 64.f);
        float d = val - mu;
        float var = d * d;
#pragma unroll
        for (int off = 1; off < 64; off <<= 1) var += __shfl_xor(var, off);
        var *= (1.f / 64.f);
        float r = d * rsqrtf(var + 1e-6f) * lns + lnb;
        out[((size_t)(t * GG) + k) * OO + o] = fmaxf(r, 0.f);
    }
}

// ---------------------------------------------------------------------------
extern "C" void kernel_launch(void* const* d_in, const int* in_sizes, int n_in,
                              void* d_out, int out_size, void* d_ws, size_t ws_size,
                              hipStream_t stream) {
    const float* x        = (const float*)d_in[0];
    const float* t_emb    = (const float*)d_in[1];
    const float* wr       = (const float*)d_in[2];
    const float* wi       = (const float*)d_in[3];
    const float* conv_w   = (const float*)d_in[4];
    const float* conv_b   = (const float*)d_in[5];
    const float* time_w   = (const float*)d_in[6];
    const float* dense_w  = (const float*)d_in[7];
    const float* ln_scale = (const float*)d_in[8];
    const float* ln_bias  = (const float*)d_in[9];
    const float* P_in     = (const float*)d_in[10];
    const float* P_out    = (const float*)d_in[11];
    const float* quad_w   = (const float*)d_in[12];

    float* ws = (float*)d_ws;
    float*  aux  = ws;                         // 512
    float2* F    = (float2*)(ws + 512);        // 524288 f2
    float2* flm  = (float2*)(ws + 1049088);    // 262144 f2
    float2* flm2 = (float2*)(ws + 1573376);    // 520192 f2
    float2* g    = (float2*)(ws + 2613760);    // 1040384 f2
    float*  Sv   = ws + 4694528;               // 16384

    float* out = (float*)d_out;

    k_pre<<<1, 128, 0, stream>>>(t_emb, dense_w, time_w, conv_w, conv_b, aux);
    k_dft<<<GG, 512, 0, stream>>>(x, quad_w, F);
    k_conv<<<GG, 128, 0, stream>>>(x, aux, Sv);
    k_leg_fwd<<<dim3(64, 2), 256, 0, stream>>>(F, P_in, flm);
    k_wmul<<<dim3(LM, MM), 256, 0, stream>>>(flm, wr, wi, flm2);
    k_leg_inv<<<dim3(MM, 4), 256, 0, stream>>>(flm2, P_out, g);
    k_final<<<dim3(GG, 2), 512, 0, stream>>>(g, Sv, aux, ln_scale, ln_bias, out);
}

// Round 4
// 340.439 us; speedup vs baseline: 1.2104x; 1.0716x over previous
//
#include <hip/hip_runtime.h>
#include <math.h>

#define LM 64      // L_MODES
#define MM 127     // 2L-1
#define GG 128     // GRID
#define CC 64      // CIN
#define OO 64      // COUT

#define TWO_PI 6.28318530717958647692f

// ---------------------------------------------------------------------------
// K1: fused DFT + conv-channel-sum + (block 256) time-MLP precompute.
// Blocks 0..255: b = (t, chalf). 256 threads: k = tx&63, cgl = tx>>6 (8 ch each).
//   F[(t*64+k)*CC + c] = sum_n x[t,n,c] e^{-i 2pi k n/128} * (2pi/G)*quad_w[t]
//   Sv[ch][t][n] = (ch==0)*bsum + sum_{c in half} x[t,n,c]*cwsum[c]
// Block 256: aux = [psi(128) | tvec(64)]
__global__ __launch_bounds__(256) void k_dft(const float* __restrict__ x,
                                             const float* __restrict__ quad_w,
                                             const float* __restrict__ conv_w,
                                             const float* __restrict__ conv_b,
                                             const float* __restrict__ t_emb,
                                             const float* __restrict__ dense_w,
                                             const float* __restrict__ time_w,
                                             float2* __restrict__ F,
                                             float* __restrict__ Sv,
                                             float* __restrict__ aux) {
    int b = blockIdx.x;
    int tx = threadIdx.x;

    if (b == 256) {
        // time-MLP: psi = t_emb @ dense_w ; tvec[o] = sum_j time_w[o,j]*psi[j]
        __shared__ float psis[128];
        if (tx < 128) {
            float acc = 0.f;
            for (int tq = 0; tq < 256; ++tq) acc += t_emb[tq] * dense_w[tq * 128 + tx];
            psis[tx] = acc;
            aux[tx] = acc;
        }
        __syncthreads();
        if (tx < 64) {
            float tv = 0.f;
            for (int q = 0; q < 64; ++q) tv += time_w[tx * 64 + q] * psis[q];
            aux[128 + tx] = tv;
        }
        return;
    }

    int t = b >> 1, ch = b & 1;
    int c0base = ch * 32;

    __shared__ __align__(16) float xs[GG * 32];  // [n][c-local] 16 KB
    __shared__ float2 tab[GG];
    __shared__ float cwsl[32];
    __shared__ float Sp[2][GG];
    __shared__ float bsum_s;

    // stage x[t][:, c0base..c0base+32) -- float4 coalesced
    {
        const float* xp = x + (size_t)t * GG * CC + c0base;
        for (int idx = tx; idx < GG * 32 / 4; idx += 256) {
            int n = idx >> 3, cq = idx & 7;
            *(float4*)&xs[n * 32 + cq * 4] = *(const float4*)&xp[n * CC + cq * 4];
        }
    }
    if (tx < GG) {
        float ang = (TWO_PI / GG) * tx;
        tab[tx] = make_float2(cosf(ang), sinf(ang));
    }
    if (tx >= 128 && tx < 160) {
        int c = c0base + (tx - 128);
        float s = 0.f;
        for (int o = 0; o < OO; ++o) s += conv_w[c * OO + o];
        cwsl[tx - 128] = s;
    }
    if (tx == 160) {
        float bs = 0.f;
        for (int o = 0; o < OO; ++o) bs += conv_b[o];
        bsum_s = bs;
    }
    __syncthreads();

    int k = tx & 63, cgl = tx >> 6;
    int c0 = cgl * 8;

    float sr[8], si[8];
#pragma unroll
    for (int j = 0; j < 8; ++j) { sr[j] = 0.f; si[j] = 0.f; }

    int kn = 0;
    for (int n = 0; n < GG; ++n) {
        float2 w = tab[kn];
        const float4 v0 = *(const float4*)&xs[n * 32 + c0];
        const float4 v1 = *(const float4*)&xs[n * 32 + c0 + 4];
        float vv[8] = {v0.x, v0.y, v0.z, v0.w, v1.x, v1.y, v1.z, v1.w};
#pragma unroll
        for (int j = 0; j < 8; ++j) {
            sr[j] += vv[j] * w.x;
            si[j] -= vv[j] * w.y;
        }
        kn = (kn + k) & (GG - 1);
    }
    float sc = (TWO_PI / GG) * quad_w[t];

    // direct store: 8 channels = 4 float4 per thread
    {
        float2* Fp = F + ((size_t)t * 64 + k) * CC + c0base + c0;
#pragma unroll
        for (int q = 0; q < 4; ++q) {
            float4 v = make_float4(sr[2 * q] * sc, si[2 * q] * sc,
                                   sr[2 * q + 1] * sc, si[2 * q + 1] * sc);
            *(float4*)&Fp[2 * q] = v;
        }
    }

    // conv channel-sum partial over this block's 32 channels (xs still valid)
    {
        int n2 = tx & 127, h = tx >> 7;  // h in {0,1}, 16 channels each
        float p = 0.f;
#pragma unroll
        for (int j = 0; j < 16; ++j) p += xs[n2 * 32 + h * 16 + j] * cwsl[h * 16 + j];
        Sp[h][n2] = p;
    }
    __syncthreads();
    if (tx < GG) {
        float v = Sp[0][tx] + Sp[1][tx] + (ch == 0 ? bsum_s : 0.f);
        Sv[(size_t)ch * GG * GG + t * GG + tx] = v;
    }
}

// ---------------------------------------------------------------------------
// K2: forward Legendre. Block per (m, l-half). 256 threads.
__global__ __launch_bounds__(256) void k_leg_fwd(const float2* __restrict__ F,
                                                 const float* __restrict__ P_in,
                                                 float2* __restrict__ flm) {
    int m = blockIdx.x;      // 0..63
    int lh = blockIdx.y;     // 0..1
    int l0 = lh * 32;
    if (l0 + 31 < m) return;

    __shared__ __align__(16) float2 Fs[64 * 64];   // 32 KB
    __shared__ __align__(16) float  Ps[128 * 36];  // 18 KB
    int tx = threadIdx.x;
    int c = tx & 63, lg = tx >> 6;

    for (int idx = tx; idx < 32 * 128; idx += 256) {
        int lr = idx >> 7, t = idx & 127;
        Ps[t * 36 + lr] = P_in[((size_t)(l0 + lr) * MM + 63 + m) * GG + t];
    }

    float sr[8], si[8];
#pragma unroll
    for (int j = 0; j < 8; ++j) { sr[j] = 0.f; si[j] = 0.f; }

    for (int tp = 0; tp < 2; ++tp) {
        __syncthreads();
        for (int idx = tx; idx < 64 * 64; idx += 256) {
            int tl = idx >> 6, cc = idx & 63;
            Fs[idx] = F[((size_t)(tp * 64 + tl) * 64 + m) * CC + cc];
        }
        __syncthreads();
        for (int tl = 0; tl < 64; ++tl) {
            int t = tp * 64 + tl;
            float2 f = Fs[tl * 64 + c];
            const float* pp = &Ps[t * 36 + lg * 8];
            float4 p0 = *(const float4*)pp;
            float4 p1 = *(const float4*)(pp + 4);
            float pv[8] = {p0.x, p0.y, p0.z, p0.w, p1.x, p1.y, p1.z, p1.w};
#pragma unroll
            for (int j = 0; j < 8; ++j) {
                sr[j] += f.x * pv[j];
                si[j] += f.y * pv[j];
            }
        }
    }
#pragma unroll
    for (int j = 0; j < 8; ++j) {
        int l = l0 + lg * 8 + j;
        if (l >= m) flm[((size_t)l * 64 + m) * CC + c] = make_float2(sr[j], si[j]);
    }
}

// ---------------------------------------------------------------------------
// K3: complex channel mix, float4 weight loads. Block per (l,mi), 256 threads.
// Thread: ol = tx&15 (o = 4*ol..4*ol+3), ig = tx>>4 (i = 4*ig..4*ig+3).
__global__ __launch_bounds__(256) void k_wmul(const float2* __restrict__ flm,
                                              const float* __restrict__ wr,
                                              const float* __restrict__ wi,
                                              float2* __restrict__ flm2) {
    int l = blockIdx.x, mi = blockIdx.y;
    int m = mi - 63;
    int am = m < 0 ? -m : m;
    if (l < am) return;
    __shared__ float2 fs[CC];
    __shared__ float2 part[16][CC];  // 8 KB
    int tx = threadIdx.x, ol = tx & 15, ig = tx >> 4;
    if (tx < 64) {
        float2 f = flm[((size_t)l * 64 + am) * CC + tx];
        if (m < 0) {
            float sgn = (am & 1) ? -1.f : 1.f;
            f.x *= sgn;
            f.y *= -sgn;
        }
        fs[tx] = f;
    }
    __syncthreads();
    size_t base = ((size_t)(l * MM + mi) * CC) * OO;
    const float4* wr4 = (const float4*)(wr + base);
    const float4* wi4 = (const float4*)(wi + base);
    float ar[4] = {0.f, 0.f, 0.f, 0.f}, ai[4] = {0.f, 0.f, 0.f, 0.f};
#pragma unroll
    for (int di = 0; di < 4; ++di) {
        int i = ig * 4 + di;
        float4 a = wr4[i * 16 + ol];
        float4 b = wi4[i * 16 + ol];
        float2 f = fs[i];
        ar[0] += f.x * a.x - f.y * b.x;  ai[0] += f.x * b.x + f.y * a.x;
        ar[1] += f.x * a.y - f.y * b.y;  ai[1] += f.x * b.y + f.y * a.y;
        ar[2] += f.x * a.z - f.y * b.z;  ai[2] += f.x * b.z + f.y * a.z;
        ar[3] += f.x * a.w - f.y * b.w;  ai[3] += f.x * b.w + f.y * a.w;
    }
#pragma unroll
    for (int j = 0; j < 4; ++j) part[ig][ol * 4 + j] = make_float2(ar[j], ai[j]);
    __syncthreads();
    if (tx < 64) {
        float rr = 0.f, ri = 0.f;
#pragma unroll
        for (int q = 0; q < 16; ++q) {
            float2 p = part[q][tx];
            rr += p.x;
            ri += p.y;
        }
        flm2[(size_t)(l * MM + mi) * OO + tx] = make_float2(rr, ri);
    }
}

// ---------------------------------------------------------------------------
// K4: inverse Legendre. Block per (mi, th(2) x oh(2)), 256 threads.
__global__ __launch_bounds__(256) void k_leg_inv(const float2* __restrict__ flm2,
                                                 const float* __restrict__ P_out,
                                                 float2* __restrict__ g) {
    int mi = blockIdx.x;
    int th = blockIdx.y >> 1, oh = blockIdx.y & 1;
    int t0 = th * 64, o0 = oh * 32;

    __shared__ __align__(16) float2 Ws[64 * 32]; // 32 KB
    __shared__ __align__(16) float  Ps[64 * 64]; // 16 KB
    int tx = threadIdx.x;
    int ol = tx & 31, tg = tx >> 5;
    int o = o0 + ol;

    for (int idx = tx; idx < 64 * 32; idx += 256) {
        int ls = idx >> 5, oo = idx & 31;
        Ws[idx] = flm2[(size_t)(ls * MM + mi) * OO + o0 + oo];
    }
    for (int idx = tx; idx < 64 * 64; idx += 256) {
        int ls = idx >> 6, tt = idx & 63;
        Ps[idx] = P_out[((size_t)ls * MM + mi) * GG + t0 + tt];
    }
    __syncthreads();

    float gr[8], gi[8];
#pragma unroll
    for (int j = 0; j < 8; ++j) { gr[j] = 0.f; gi[j] = 0.f; }

    for (int l = 0; l < 64; ++l) {
        float2 wv = Ws[l * 32 + ol];
        const float* pp = &Ps[l * 64 + tg * 8];
        float4 p0 = *(const float4*)pp;
        float4 p1 = *(const float4*)(pp + 4);
        float pv[8] = {p0.x, p0.y, p0.z, p0.w, p1.x, p1.y, p1.z, p1.w};
#pragma unroll
        for (int j = 0; j < 8; ++j) {
            gr[j] += wv.x * pv[j];
            gi[j] += wv.y * pv[j];
        }
    }
#pragma unroll
    for (int j = 0; j < 8; ++j) {
        int t = t0 + tg * 8 + j;
        g[((size_t)t * MM + mi) * OO + o] = make_float2(gr[j], gi[j]);
    }
}

// ---------------------------------------------------------------------------
// K5: Fourier synthesis (Horner) + time-mod branch + LN + ReLU.
__global__ __launch_bounds__(512) void k_final(const float2* __restrict__ g,
                                               const float* __restrict__ Sv,
                                               const float* __restrict__ aux,
                                               const float* __restrict__ ln_scale,
                                               const float* __restrict__ ln_bias,
                                               float* __restrict__ out) {
    __shared__ float2 gs[64 * 64]; // 32 KB, two mi-passes
    __shared__ float Ss[64];
    int t = blockIdx.x, kh = blockIdx.y;
    int tx = threadIdx.x;
    int o = tx & 63, kg = tx >> 6;

    if (tx < 64)
        Ss[tx] = Sv[t * GG + kh * 64 + tx] + Sv[GG * GG + t * GG + kh * 64 + tx];

    float zr[8], zi[8], accr[8], acci[8];
#pragma unroll
    for (int j = 0; j < 8; ++j) {
        int k = kh * 64 + kg * 8 + j;
        float phi = (TWO_PI / GG) * k;
        float s, c;
        __sincosf(phi, &s, &c);
        zr[j] = c; zi[j] = s;
        accr[j] = 0.f; acci[j] = 0.f;
    }

    for (int pass = 0; pass < 2; ++pass) {
        int mbase = (pass == 0) ? 64 : 0;
        int cnt = (pass == 0) ? 63 : 64;
        __syncthreads();
        for (int idx = tx; idx < cnt * 64; idx += 512) {
            int mm = idx >> 6, oo = idx & 63;
            gs[idx] = g[((size_t)t * MM + mbase + mm) * OO + oo];
        }
        __syncthreads();
        for (int mm = cnt - 1; mm >= 0; --mm) {
            float2 gv = gs[mm * 64 + o];
#pragma unroll
            for (int j = 0; j < 8; ++j) {
                float tr = accr[j] * zr[j] - acci[j] * zi[j] + gv.x;
                float ti = accr[j] * zi[j] + acci[j] * zr[j] + gv.y;
                accr[j] = tr; acci[j] = ti;
            }
        }
    }

    float tvec = aux[128 + o], bt = aux[64 + o];
    float lns = ln_scale[o], lnb = ln_bias[o];
#pragma unroll
    for (int j = 0; j < 8; ++j) {
        int k = kh * 64 + kg * 8 + j;
        float phi = (TWO_PI / GG) * k;
        float s63, c63;
        sincosf(63.f * phi, &s63, &c63);
        float xsp = accr[j] * c63 + acci[j] * s63; // Re(e^{-i63phi} * H)
        float val = xsp + tvec * Ss[k - kh * 64] + bt;

        float mu = val;
#pragma unroll
        for (int off = 1; off < 64; off <<= 1) mu += __shfl_xor(mu, off);
        mu *= (1.f / 64.f);
        float d = val - mu;
        float var = d * d;
#pragma unroll
        for (int off = 1; off < 64; off <<= 1) var += __shfl_xor(var, off);
        var *= (1.f / 64.f);
        float r = d * rsqrtf(var + 1e-6f) * lns + lnb;
        out[((size_t)(t * GG) + k) * OO + o] = fmaxf(r, 0.f);
    }
}

// ---------------------------------------------------------------------------
extern "C" void kernel_launch(void* const* d_in, const int* in_sizes, int n_in,
                              void* d_out, int out_size, void* d_ws, size_t ws_size,
                              hipStream_t stream) {
    const float* x        = (const float*)d_in[0];
    const float* t_emb    = (const float*)d_in[1];
    const float* wr       = (const float*)d_in[2];
    const float* wi       = (const float*)d_in[3];
    const float* conv_w   = (const float*)d_in[4];
    const float* conv_b   = (const float*)d_in[5];
    const float* time_w   = (const float*)d_in[6];
    const float* dense_w  = (const float*)d_in[7];
    const float* ln_scale = (const float*)d_in[8];
    const float* ln_bias  = (const float*)d_in[9];
    const float* P_in     = (const float*)d_in[10];
    const float* P_out    = (const float*)d_in[11];
    const float* quad_w   = (const float*)d_in[12];

    float* ws = (float*)d_ws;
    float*  aux  = ws;                         // 512
    float2* F    = (float2*)(ws + 512);        // 524288 f2
    float2* flm  = (float2*)(ws + 1049088);    // 262144 f2
    float2* flm2 = (float2*)(ws + 1573376);    // 520192 f2
    float2* g    = (float2*)(ws + 2613760);    // 1040384 f2
    float*  Sv   = ws + 4694528;               // 32768 (2 x 128 x 128)

    float* out = (float*)d_out;

    k_dft<<<257, 256, 0, stream>>>(x, quad_w, conv_w, conv_b, t_emb, dense_w, time_w,
                                   F, Sv, aux);
    k_leg_fwd<<<dim3(64, 2), 256, 0, stream>>>(F, P_in, flm);
    k_wmul<<<dim3(LM, MM), 256, 0, stream>>>(flm, wr, wi, flm2);
    k_leg_inv<<<dim3(MM, 4), 256, 0, stream>>>(flm2, P_out, g);
    k_final<<<dim3(GG, 2), 512, 0, stream>>>(g, Sv, aux, ln_scale, ln_bias, out);
}